// Round 5
// baseline (250.668 us; speedup 1.0000x reference)
//
#include <hip/hip_runtime.h>

// Problem constants (fixed by the reference's setup_inputs).
constexpr int N = 8192;          // row length
constexpr int K = 64;            // top-k
constexpr int THREADS = 256;
constexpr int WAVES = THREADS / 64;
constexpr int VEC = N / THREADS / 4;  // 8 float4 loads per thread per pass
constexpr int CAP = 1024;        // candidate capacity (expected fill ~250)

// Map fp32 bits to an unsigned key with the same total order as float.
__device__ __forceinline__ unsigned orderable(float f) {
    unsigned x = __float_as_uint(f);
    return (x & 0x80000000u) ? ~x : (x | 0x80000000u);
}

// R4 post-mortem: full-row 2048-bin histogram select carries ~46us of
// phase/barrier/atomic cost regardless of occupancy. The input tail is known
// (N(0,1)+Gumbel: P(g>t) ~ e^{0.5-t}), so a fixed threshold g>4.0 leaves
// ~250 candidates/row (P(<64) ~ e^-30). Fast path: one streaming pass
// (zeros + compact), exact rank among candidates, scatter 64 ones.
// Fallback: fully general streaming radix select (any input, never taken here).
__global__ __launch_bounds__(THREADS, 4)
void gumbel_topk_onehot(const float* __restrict__ logits,
                        const float* __restrict__ noise,
                        float* __restrict__ out)
{
    __shared__ unsigned smem[2 * CAP];   // fast: candk|candi (8 KB); fallback: hist[2048]
    __shared__ unsigned wavesum[WAVES];
    __shared__ unsigned cnt;
    __shared__ unsigned sel_bin, sel_kth, sel_cnt;

    unsigned* candk = smem;          // candidate keys
    unsigned* candi = smem + CAP;    // candidate element indices
    unsigned* hist  = smem;          // fallback-only alias (2048 bins)

    const int tid  = threadIdx.x;
    const int lane = tid & 63;
    const int wave = tid >> 6;
    const long long row = blockIdx.x;

    const float4* lrow = (const float4*)(logits + row * (long long)N);
    const float4* nrow = (const float4*)(noise  + row * (long long)N);
    float4* orow = (float4*)(out + row * (long long)N);

    const unsigned T0 = orderable(4.0f);   // folds to a constant

    if (tid == 0) cnt = 0;
    __syncthreads();

    // ======== Pass 1: stream row, write zeros, compact survivors ========
#pragma unroll
    for (int i = 0; i < VEC; ++i) {
        int idx = tid + i * THREADS;     // float4 index, coalesced
        float4 a = lrow[idx];
        float4 b = nrow[idx];
        unsigned k0 = orderable(a.x + b.x);
        unsigned k1 = orderable(a.y + b.y);
        unsigned k2 = orderable(a.z + b.z);
        unsigned k3 = orderable(a.w + b.w);
        orow[idx] = make_float4(0.f, 0.f, 0.f, 0.f);
        if (k0 > T0) { unsigned p = atomicAdd(&cnt, 1u); if (p < CAP) { candk[p] = k0; candi[p] = 4u*idx + 0u; } }
        if (k1 > T0) { unsigned p = atomicAdd(&cnt, 1u); if (p < CAP) { candk[p] = k1; candi[p] = 4u*idx + 1u; } }
        if (k2 > T0) { unsigned p = atomicAdd(&cnt, 1u); if (p < CAP) { candk[p] = k2; candi[p] = 4u*idx + 2u; } }
        if (k3 > T0) { unsigned p = atomicAdd(&cnt, 1u); if (p < CAP) { candk[p] = k3; candi[p] = 4u*idx + 3u; } }
    }
    __syncthreads();   // candidates visible; zero-stores drained (vmcnt at barrier)

    const unsigned n = cnt;
    if (n >= (unsigned)K && n <= (unsigned)CAP) {
        // ---- Exact select among n candidates (jax.lax.top_k semantics:
        // value desc, index asc). rank(t) = #{j : j beats t}; selected iff <K.
        for (unsigned t = tid; t < n; t += THREADS) {
            unsigned kt = candk[t], it = candi[t];
            unsigned rank = 0;
            for (unsigned j = 0; j < n; ++j) {
                unsigned kj = candk[j];   // broadcast read, conflict-free
                unsigned ij = candi[j];
                rank += (kj > kt || (kj == kt && ij < it)) ? 1u : 0u;
            }
            if (rank < (unsigned)K)
                out[row * (long long)N + it] = 1.0f;
        }
        return;   // block-uniform branch
    }

    // ================= Fallback: general streaming radix select =================
    // (distribution-free correctness; overwrites the whole output row)
    unsigned kth = K;

#define SELECT_BIN(BPT)                                                      \
    {                                                                        \
        unsigned p = 0;                                                      \
        _Pragma("unroll")                                                    \
        for (int j = 0; j < (BPT); ++j) p += hist[tid * (BPT) + j];          \
        unsigned s = p;                                                      \
        _Pragma("unroll")                                                    \
        for (int off = 1; off < 64; off <<= 1) {                             \
            unsigned v = __shfl_down(s, off);                                \
            if (lane + off < 64) s += v;                                     \
        }                                                                    \
        if (lane == 0) wavesum[wave] = s;                                    \
        __syncthreads();                                                     \
        unsigned S = s;                                                      \
        _Pragma("unroll")                                                    \
        for (int w = 0; w < WAVES; ++w) if (w > wave) S += wavesum[w];       \
        unsigned Snext = S - p;                                              \
        if (S >= kth && Snext < kth) {                                       \
            unsigned cum = Snext;                                            \
            for (int j = (BPT) - 1; j >= 0; --j) {                           \
                unsigned c = hist[tid * (BPT) + j];                          \
                if (cum + c >= kth) {                                        \
                    sel_bin = (unsigned)(tid * (BPT) + j);                   \
                    sel_kth = kth - cum;                                     \
                    sel_cnt = c;                                             \
                    break;                                                   \
                }                                                            \
                cum += c;                                                    \
            }                                                                \
        }                                                                    \
        __syncthreads();                                                     \
    }

    // ---- Round 1: bits [31:21] ----
    {
        uint4 z = make_uint4(0,0,0,0);
        for (int i = tid; i < 512; i += THREADS) ((uint4*)hist)[i] = z;
    }
    __syncthreads();
#pragma unroll
    for (int i = 0; i < VEC; ++i) {
        int idx = tid + i * THREADS;
        float4 a = lrow[idx];
        float4 b = nrow[idx];
        atomicAdd(&hist[orderable(a.x + b.x) >> 21], 1u);
        atomicAdd(&hist[orderable(a.y + b.y) >> 21], 1u);
        atomicAdd(&hist[orderable(a.z + b.z) >> 21], 1u);
        atomicAdd(&hist[orderable(a.w + b.w) >> 21], 1u);
    }
    __syncthreads();
    SELECT_BIN(8)
    const unsigned b1 = sel_bin;
    kth = sel_kth;
    __syncthreads();

    // ---- Round 2: bits [20:10] ----
    {
        uint4 z = make_uint4(0,0,0,0);
        for (int i = tid; i < 512; i += THREADS) ((uint4*)hist)[i] = z;
    }
    __syncthreads();
#pragma unroll
    for (int i = 0; i < VEC; ++i) {
        int idx = tid + i * THREADS;
        float4 a = lrow[idx];
        float4 b = nrow[idx];
        unsigned k0 = orderable(a.x + b.x), k1 = orderable(a.y + b.y);
        unsigned k2 = orderable(a.z + b.z), k3 = orderable(a.w + b.w);
        if ((k0 >> 21) == b1) atomicAdd(&hist[(k0 >> 10) & 0x7FFu], 1u);
        if ((k1 >> 21) == b1) atomicAdd(&hist[(k1 >> 10) & 0x7FFu], 1u);
        if ((k2 >> 21) == b1) atomicAdd(&hist[(k2 >> 10) & 0x7FFu], 1u);
        if ((k3 >> 21) == b1) atomicAdd(&hist[(k3 >> 10) & 0x7FFu], 1u);
    }
    __syncthreads();
    SELECT_BIN(8)
    const unsigned b2 = sel_bin;
    kth = sel_kth;
    __syncthreads();

    // ---- Round 3: bits [9:0] ----
    {
        uint4 z = make_uint4(0,0,0,0);
        for (int i = tid; i < 256; i += THREADS) ((uint4*)hist)[i] = z;
    }
    __syncthreads();
    {
        const unsigned pfx = (b1 << 11) | b2;
#pragma unroll
        for (int i = 0; i < VEC; ++i) {
            int idx = tid + i * THREADS;
            float4 a = lrow[idx];
            float4 b = nrow[idx];
            unsigned k0 = orderable(a.x + b.x), k1 = orderable(a.y + b.y);
            unsigned k2 = orderable(a.z + b.z), k3 = orderable(a.w + b.w);
            if ((k0 >> 10) == pfx) atomicAdd(&hist[k0 & 0x3FFu], 1u);
            if ((k1 >> 10) == pfx) atomicAdd(&hist[k1 & 0x3FFu], 1u);
            if ((k2 >> 10) == pfx) atomicAdd(&hist[k2 & 0x3FFu], 1u);
            if ((k3 >> 10) == pfx) atomicAdd(&hist[k3 & 0x3FFu], 1u);
        }
    }
    __syncthreads();
    SELECT_BIN(4)
    const unsigned b3      = sel_bin;
    const unsigned take_eq = sel_kth;
    const unsigned c_eq    = sel_cnt;

    const unsigned T = (b1 << 21) | (b2 << 10) | b3;
    const bool fast = (take_eq == c_eq);

    // ---- Output pass (overwrites row) ----
#pragma unroll
    for (int i = 0; i < VEC; ++i) {
        int idx = tid + i * THREADS;
        float4 a = lrow[idx];
        float4 b = nrow[idx];
        unsigned k0 = orderable(a.x + b.x), k1 = orderable(a.y + b.y);
        unsigned k2 = orderable(a.z + b.z), k3 = orderable(a.w + b.w);
        float4 o;
        o.x = (k0 > T || (fast && k0 == T)) ? 1.0f : 0.0f;
        o.y = (k1 > T || (fast && k1 == T)) ? 1.0f : 0.0f;
        o.z = (k2 > T || (fast && k2 == T)) ? 1.0f : 0.0f;
        o.w = (k3 > T || (fast && k3 == T)) ? 1.0f : 0.0f;
        orow[idx] = o;
    }

    // Boundary-straddling tie: lowest indices win (jax.lax.top_k).
    if (!fast) {
        __syncthreads();
        if (tid == 0) {
            const float* lf = logits + row * (long long)N;
            const float* nf = noise  + row * (long long)N;
            float* of = out + row * (long long)N;
            unsigned c = 0;
            for (int i = 0; i < N; ++i) {
                if (orderable(lf[i] + nf[i]) == T) {
                    of[i] = 1.0f;
                    if (++c == take_eq) break;
                }
            }
        }
    }
#undef SELECT_BIN
}

extern "C" void kernel_launch(void* const* d_in, const int* in_sizes, int n_in,
                              void* d_out, int out_size, void* d_ws, size_t ws_size,
                              hipStream_t stream) {
    const float* logits = (const float*)d_in[0];
    const float* noise  = (const float*)d_in[1];
    float* out = (float*)d_out;
    const int rows = in_sizes[0] / N;   // 2048
    gumbel_topk_onehot<<<rows, THREADS, 0, stream>>>(logits, noise, out);
}

// Round 6
// 182.803 us; speedup vs baseline: 1.3712x; 1.3712x over previous
//
#include <hip/hip_runtime.h>

// Problem constants (fixed by the reference's setup_inputs).
constexpr int N = 8192;          // row length
constexpr int K = 64;            // top-k
constexpr int THREADS = 256;
constexpr int WAVES = THREADS / 64;
constexpr int VEC = N / THREADS / 4;  // 8 float4 loads per thread per pass
constexpr int SEGCAP = 256;      // per-wave candidate capacity (expected ~62)

// Map fp32 bits to an unsigned key with the same total order as float.
__device__ __forceinline__ unsigned orderable(float f) {
    unsigned x = __float_as_uint(f);
    return (x & 0x80000000u) ? ~x : (x | 0x80000000u);
}

// R5 post-mortem: per-element atomicAdd-with-return compaction = 32 divergent
// ds_add_rtn round-trips per thread (serialized ~120cy each) at 16-wave
// occupancy -> latency-bound at 12% HBM. This version: ballot-prefix
// compaction into per-wave LDS segments (no atomics, no rtn dependency),
// ONE barrier on the fast path, 8 blocks/CU. Candidates packed
// (key<<32)|(N-1-idx) so "beats" (value desc, index asc — jax.lax.top_k
// semantics) is a single u64 compare.
__global__ __launch_bounds__(THREADS, 8)
void gumbel_topk_onehot(const float* __restrict__ logits,
                        const float* __restrict__ noise,
                        float* __restrict__ out)
{
    __shared__ unsigned long long seg[WAVES * SEGCAP];  // 8 KB per-wave segments
    __shared__ unsigned long long dst[WAVES * SEGCAP];  // 8 KB flattened
    __shared__ unsigned counts[WAVES];
    __shared__ unsigned wavesum[WAVES];
    __shared__ unsigned sel_bin, sel_kth, sel_cnt;

    unsigned* hist = (unsigned*)seg;   // fallback alias: 2048 bins = 8 KB

    const int tid  = threadIdx.x;
    const int lane = tid & 63;
    const int wave = tid >> 6;
    const long long row = blockIdx.x;

    const float4* lrow = (const float4*)(logits + row * (long long)N);
    const float4* nrow = (const float4*)(noise  + row * (long long)N);
    float4* orow = (float4*)(out + row * (long long)N);

    const unsigned T0 = orderable(4.0f);        // ~250 survivors/row expected
    const unsigned long long lt = (1ull << lane) - 1ull;

    // ======== Pass 1: stream row, write zeros, ballot-compact survivors ========
    unsigned wcnt = 0;   // uniform across the wave (sum of ballot popcounts)

#define EMIT(kk, elem)                                                        \
    {                                                                         \
        bool p = (kk) > T0;                                                   \
        unsigned long long m = __ballot(p);                                   \
        if (p) {                                                              \
            unsigned pos = wcnt + (unsigned)__popcll(m & lt);                 \
            if (pos < (unsigned)SEGCAP)                                       \
                seg[wave * SEGCAP + pos] =                                    \
                    ((unsigned long long)(kk) << 32) |                        \
                    (unsigned long long)(unsigned)(N - 1 - (elem));           \
        }                                                                     \
        wcnt += (unsigned)__popcll(m);                                        \
    }

#pragma unroll
    for (int i = 0; i < VEC; ++i) {
        int idx = tid + i * THREADS;     // float4 index, coalesced
        float4 a = lrow[idx];
        float4 b = nrow[idx];
        unsigned k0 = orderable(a.x + b.x);
        unsigned k1 = orderable(a.y + b.y);
        unsigned k2 = orderable(a.z + b.z);
        unsigned k3 = orderable(a.w + b.w);
        orow[idx] = make_float4(0.f, 0.f, 0.f, 0.f);
        EMIT(k0, 4 * idx + 0)
        EMIT(k1, 4 * idx + 1)
        EMIT(k2, 4 * idx + 2)
        EMIT(k3, 4 * idx + 3)
    }
#undef EMIT
    if (lane == 0) counts[wave] = wcnt;
    __syncthreads();   // zero-stores drained (vmcnt at barrier); segments visible

    const unsigned c0 = counts[0], c1 = counts[1], c2 = counts[2], c3 = counts[3];
    const unsigned n = c0 + c1 + c2 + c3;
    const bool ok = (n >= (unsigned)K) &&
                    (c0 <= SEGCAP) && (c1 <= SEGCAP) && (c2 <= SEGCAP) && (c3 <= SEGCAP);

    if (ok) {   // block-uniform branch
        // ---- Flatten segments into contiguous dst ----
        const unsigned offs[WAVES] = {0u, c0, c0 + c1, c0 + c1 + c2};
        const unsigned cws[WAVES]  = {c0, c1, c2, c3};
#pragma unroll
        for (int w = 0; w < WAVES; ++w)
            for (unsigned l = tid; l < cws[w]; l += THREADS)
                dst[offs[w] + l] = seg[w * SEGCAP + l];
        __syncthreads();

        // ---- Exact rank among n candidates; top-K scatter ----
        for (unsigned t = tid; t < n; t += THREADS) {
            unsigned long long ct = dst[t];
            unsigned rank = 0;
            for (unsigned j = 0; j < n; ++j)          // broadcast LDS reads
                rank += (dst[j] > ct) ? 1u : 0u;
            if (rank < (unsigned)K) {
                unsigned elem = (unsigned)(N - 1) - (unsigned)(ct & 0xFFFFFFFFull);
                out[row * (long long)N + elem] = 1.0f;
            }
        }
        return;
    }

    // ================= Fallback: general streaming radix select =================
    // Distribution-free correctness; overwrites the whole output row.
    unsigned kth = K;

#define SELECT_BIN(BPT)                                                      \
    {                                                                        \
        unsigned p = 0;                                                      \
        _Pragma("unroll")                                                    \
        for (int j = 0; j < (BPT); ++j) p += hist[tid * (BPT) + j];          \
        unsigned s = p;                                                      \
        _Pragma("unroll")                                                    \
        for (int off = 1; off < 64; off <<= 1) {                             \
            unsigned v = __shfl_down(s, off);                                \
            if (lane + off < 64) s += v;                                     \
        }                                                                    \
        if (lane == 0) wavesum[wave] = s;                                    \
        __syncthreads();                                                     \
        unsigned S = s;                                                      \
        _Pragma("unroll")                                                    \
        for (int w = 0; w < WAVES; ++w) if (w > wave) S += wavesum[w];       \
        unsigned Snext = S - p;                                              \
        if (S >= kth && Snext < kth) {                                       \
            unsigned cum = Snext;                                            \
            for (int j = (BPT) - 1; j >= 0; --j) {                           \
                unsigned c = hist[tid * (BPT) + j];                          \
                if (cum + c >= kth) {                                        \
                    sel_bin = (unsigned)(tid * (BPT) + j);                   \
                    sel_kth = kth - cum;                                     \
                    sel_cnt = c;                                             \
                    break;                                                   \
                }                                                            \
                cum += c;                                                    \
            }                                                                \
        }                                                                    \
        __syncthreads();                                                     \
    }

    // ---- Round 1: bits [31:21] ----
    {
        uint4 z = make_uint4(0, 0, 0, 0);
        for (int i = tid; i < 512; i += THREADS) ((uint4*)hist)[i] = z;
    }
    __syncthreads();
#pragma unroll
    for (int i = 0; i < VEC; ++i) {
        int idx = tid + i * THREADS;
        float4 a = lrow[idx];
        float4 b = nrow[idx];
        atomicAdd(&hist[orderable(a.x + b.x) >> 21], 1u);
        atomicAdd(&hist[orderable(a.y + b.y) >> 21], 1u);
        atomicAdd(&hist[orderable(a.z + b.z) >> 21], 1u);
        atomicAdd(&hist[orderable(a.w + b.w) >> 21], 1u);
    }
    __syncthreads();
    SELECT_BIN(8)
    const unsigned b1 = sel_bin;
    kth = sel_kth;
    __syncthreads();

    // ---- Round 2: bits [20:10] ----
    {
        uint4 z = make_uint4(0, 0, 0, 0);
        for (int i = tid; i < 512; i += THREADS) ((uint4*)hist)[i] = z;
    }
    __syncthreads();
#pragma unroll
    for (int i = 0; i < VEC; ++i) {
        int idx = tid + i * THREADS;
        float4 a = lrow[idx];
        float4 b = nrow[idx];
        unsigned k0 = orderable(a.x + b.x), k1 = orderable(a.y + b.y);
        unsigned k2 = orderable(a.z + b.z), k3 = orderable(a.w + b.w);
        if ((k0 >> 21) == b1) atomicAdd(&hist[(k0 >> 10) & 0x7FFu], 1u);
        if ((k1 >> 21) == b1) atomicAdd(&hist[(k1 >> 10) & 0x7FFu], 1u);
        if ((k2 >> 21) == b1) atomicAdd(&hist[(k2 >> 10) & 0x7FFu], 1u);
        if ((k3 >> 21) == b1) atomicAdd(&hist[(k3 >> 10) & 0x7FFu], 1u);
    }
    __syncthreads();
    SELECT_BIN(8)
    const unsigned b2 = sel_bin;
    kth = sel_kth;
    __syncthreads();

    // ---- Round 3: bits [9:0] ----
    {
        uint4 z = make_uint4(0, 0, 0, 0);
        for (int i = tid; i < 256; i += THREADS) ((uint4*)hist)[i] = z;
    }
    __syncthreads();
    {
        const unsigned pfx = (b1 << 11) | b2;
#pragma unroll
        for (int i = 0; i < VEC; ++i) {
            int idx = tid + i * THREADS;
            float4 a = lrow[idx];
            float4 b = nrow[idx];
            unsigned k0 = orderable(a.x + b.x), k1 = orderable(a.y + b.y);
            unsigned k2 = orderable(a.z + b.z), k3 = orderable(a.w + b.w);
            if ((k0 >> 10) == pfx) atomicAdd(&hist[k0 & 0x3FFu], 1u);
            if ((k1 >> 10) == pfx) atomicAdd(&hist[k1 & 0x3FFu], 1u);
            if ((k2 >> 10) == pfx) atomicAdd(&hist[k2 & 0x3FFu], 1u);
            if ((k3 >> 10) == pfx) atomicAdd(&hist[k3 & 0x3FFu], 1u);
        }
    }
    __syncthreads();
    SELECT_BIN(4)
    const unsigned b3      = sel_bin;
    const unsigned take_eq = sel_kth;
    const unsigned c_eq    = sel_cnt;

    const unsigned T = (b1 << 21) | (b2 << 10) | b3;
    const bool fast = (take_eq == c_eq);

    // ---- Output pass (overwrites row) ----
#pragma unroll
    for (int i = 0; i < VEC; ++i) {
        int idx = tid + i * THREADS;
        float4 a = lrow[idx];
        float4 b = nrow[idx];
        unsigned k0 = orderable(a.x + b.x), k1 = orderable(a.y + b.y);
        unsigned k2 = orderable(a.z + b.z), k3 = orderable(a.w + b.w);
        float4 o;
        o.x = (k0 > T || (fast && k0 == T)) ? 1.0f : 0.0f;
        o.y = (k1 > T || (fast && k1 == T)) ? 1.0f : 0.0f;
        o.z = (k2 > T || (fast && k2 == T)) ? 1.0f : 0.0f;
        o.w = (k3 > T || (fast && k3 == T)) ? 1.0f : 0.0f;
        orow[idx] = o;
    }

    // Boundary-straddling tie: lowest indices win (jax.lax.top_k).
    if (!fast) {
        __syncthreads();
        if (tid == 0) {
            const float* lf = logits + row * (long long)N;
            const float* nf = noise  + row * (long long)N;
            float* of = out + row * (long long)N;
            unsigned c = 0;
            for (int i = 0; i < N; ++i) {
                if (orderable(lf[i] + nf[i]) == T) {
                    of[i] = 1.0f;
                    if (++c == take_eq) break;
                }
            }
        }
    }
#undef SELECT_BIN
}

extern "C" void kernel_launch(void* const* d_in, const int* in_sizes, int n_in,
                              void* d_out, int out_size, void* d_ws, size_t ws_size,
                              hipStream_t stream) {
    const float* logits = (const float*)d_in[0];
    const float* noise  = (const float*)d_in[1];
    float* out = (float*)d_out;
    const int rows = in_sizes[0] / N;   // 2048
    gumbel_topk_onehot<<<rows, THREADS, 0, stream>>>(logits, noise, out);
}

// Round 7
// 182.266 us; speedup vs baseline: 1.3753x; 1.0029x over previous
//
#include <hip/hip_runtime.h>

// Problem constants (fixed by the reference's setup_inputs).
constexpr int N = 8192;          // row length
constexpr int K = 64;            // top-k
constexpr int THREADS = 256;
constexpr int WAVES = THREADS / 64;
constexpr int VEC = N / THREADS / 4;  // 8 float4 loads per thread per pass
constexpr int SEGCAP = 256;      // per-wave candidate capacity (expected ~62)
constexpr int SEGSTRIDE = SEGCAP + 64;  // +64 per-lane dump slots (branchless writes)

// Map fp32 bits to an unsigned key with the same total order as float.
__device__ __forceinline__ unsigned orderable(float f) {
    unsigned x = __float_as_uint(f);
    return (x & 0x80000000u) ? ~x : (x | 0x80000000u);
}

// R6 post-mortem: divergent `if(p) ds_write` regions in the hot loop fenced
// load hoisting (VGPR=32 of 64 used, 1.8 TB/s vs R4's 3.0 on the same
// hardware shape). This version: (a) branchless compaction — every lane
// unconditionally ds_writes; non-candidates go to a per-lane dump slot
// (SEGCAP+lane, 2-way bank alias = free); (b) explicit 4-wide load chunks
// (8 back-to-back dwordx4) to force MLP; (c) zero-fill loop separated from
// the load loop. Candidates packed (key<<32)|(N-1-idx) so "beats" (value
// desc, index asc — jax.lax.top_k) is one u64 compare.
__global__ __launch_bounds__(THREADS, 8)
void gumbel_topk_onehot(const float* __restrict__ logits,
                        const float* __restrict__ noise,
                        float* __restrict__ out)
{
    __shared__ unsigned long long seg[WAVES * SEGSTRIDE];  // 10.2 KB segments+dump
    __shared__ unsigned long long dst[WAVES * SEGCAP];     // 8 KB flattened
    __shared__ unsigned counts[WAVES];
    __shared__ unsigned wavesum[WAVES];
    __shared__ unsigned sel_bin, sel_kth, sel_cnt;

    unsigned* hist = (unsigned*)seg;   // fallback alias: 2048 bins = 8 KB

    const int tid  = threadIdx.x;
    const int lane = tid & 63;
    const int wave = tid >> 6;
    const long long row = blockIdx.x;

    const float4* lrow = (const float4*)(logits + row * (long long)N);
    const float4* nrow = (const float4*)(noise  + row * (long long)N);
    float4* orow = (float4*)(out + row * (long long)N);

    const unsigned T0 = orderable(4.0f);        // ~250 survivors/row expected
    const unsigned long long lt = (1ull << lane) - 1ull;
    const unsigned dump = (unsigned)SEGCAP + (unsigned)lane;  // per-lane trash slot

    // ---- Zero-fill output row first: 8 independent fire-and-forget stores ----
#pragma unroll
    for (int i = 0; i < VEC; ++i)
        orow[tid + i * THREADS] = make_float4(0.f, 0.f, 0.f, 0.f);

    // ======== Pass 1: stream row, branchless ballot-compact survivors ========
    unsigned wcnt = 0;   // wave-uniform candidate count

#define EMIT(kk, elem)                                                        \
    {                                                                         \
        bool p = (kk) > T0;                                                   \
        unsigned long long m = __ballot(p);                                   \
        unsigned pos = wcnt + (unsigned)__popcll(m & lt);                     \
        unsigned slot = (p && pos < (unsigned)SEGCAP) ? pos : dump;           \
        seg[wave * SEGSTRIDE + slot] =                                        \
            ((unsigned long long)(kk) << 32) |                                \
            (unsigned long long)(unsigned)(N - 1 - (elem));                   \
        wcnt += (unsigned)__popcll(m);                                        \
    }

#define EMIT4(va, vb, i4)                                                     \
    {                                                                         \
        unsigned k0 = orderable((va).x + (vb).x);                             \
        unsigned k1 = orderable((va).y + (vb).y);                             \
        unsigned k2 = orderable((va).z + (vb).z);                             \
        unsigned k3 = orderable((va).w + (vb).w);                             \
        EMIT(k0, 4 * (i4) + 0)                                                \
        EMIT(k1, 4 * (i4) + 1)                                                \
        EMIT(k2, 4 * (i4) + 2)                                                \
        EMIT(k3, 4 * (i4) + 3)                                                \
    }

#pragma unroll
    for (int c = 0; c < VEC; c += 4) {
        // 8 back-to-back loads (32 dest VGPRs) -> deep MLP before any use.
        int i0 = tid + (c + 0) * THREADS;
        int i1 = tid + (c + 1) * THREADS;
        int i2 = tid + (c + 2) * THREADS;
        int i3 = tid + (c + 3) * THREADS;
        float4 a0 = lrow[i0], a1 = lrow[i1], a2 = lrow[i2], a3 = lrow[i3];
        float4 b0 = nrow[i0], b1 = nrow[i1], b2 = nrow[i2], b3 = nrow[i3];
        EMIT4(a0, b0, i0)
        EMIT4(a1, b1, i1)
        EMIT4(a2, b2, i2)
        EMIT4(a3, b3, i3)
    }
#undef EMIT4
#undef EMIT

    if (lane == 0) counts[wave] = wcnt;
    __syncthreads();   // zero-stores drained (vmcnt at barrier); segments visible

    const unsigned c0 = counts[0], c1 = counts[1], c2 = counts[2], c3 = counts[3];
    const unsigned n = c0 + c1 + c2 + c3;
    const bool ok = (n >= (unsigned)K) &&
                    (c0 <= SEGCAP) && (c1 <= SEGCAP) && (c2 <= SEGCAP) && (c3 <= SEGCAP);

    if (ok) {   // block-uniform branch
        // ---- Flatten segments into contiguous dst ----
        const unsigned offs[WAVES] = {0u, c0, c0 + c1, c0 + c1 + c2};
        const unsigned cws[WAVES]  = {c0, c1, c2, c3};
#pragma unroll
        for (int w = 0; w < WAVES; ++w)
            for (unsigned l = tid; l < cws[w]; l += THREADS)
                dst[offs[w] + l] = seg[w * SEGSTRIDE + l];
        __syncthreads();

        // ---- Exact rank among n candidates; top-K scatter ----
        for (unsigned t = tid; t < n; t += THREADS) {
            unsigned long long ct = dst[t];
            unsigned rank = 0;
            for (unsigned j = 0; j < n; ++j)          // broadcast LDS reads
                rank += (dst[j] > ct) ? 1u : 0u;
            if (rank < (unsigned)K) {
                unsigned elem = (unsigned)(N - 1) - (unsigned)(ct & 0xFFFFFFFFull);
                out[row * (long long)N + elem] = 1.0f;
            }
        }
        return;
    }

    // ================= Fallback: general streaming radix select =================
    // Distribution-free correctness; overwrites the whole output row.
    unsigned kth = K;

#define SELECT_BIN(BPT)                                                      \
    {                                                                        \
        unsigned p = 0;                                                      \
        _Pragma("unroll")                                                    \
        for (int j = 0; j < (BPT); ++j) p += hist[tid * (BPT) + j];          \
        unsigned s = p;                                                      \
        _Pragma("unroll")                                                    \
        for (int off = 1; off < 64; off <<= 1) {                             \
            unsigned v = __shfl_down(s, off);                                \
            if (lane + off < 64) s += v;                                     \
        }                                                                    \
        if (lane == 0) wavesum[wave] = s;                                    \
        __syncthreads();                                                     \
        unsigned S = s;                                                      \
        _Pragma("unroll")                                                    \
        for (int w = 0; w < WAVES; ++w) if (w > wave) S += wavesum[w];       \
        unsigned Snext = S - p;                                              \
        if (S >= kth && Snext < kth) {                                       \
            unsigned cum = Snext;                                            \
            for (int j = (BPT) - 1; j >= 0; --j) {                           \
                unsigned c = hist[tid * (BPT) + j];                          \
                if (cum + c >= kth) {                                        \
                    sel_bin = (unsigned)(tid * (BPT) + j);                   \
                    sel_kth = kth - cum;                                     \
                    sel_cnt = c;                                             \
                    break;                                                   \
                }                                                            \
                cum += c;                                                    \
            }                                                                \
        }                                                                    \
        __syncthreads();                                                     \
    }

    // ---- Round 1: bits [31:21] ----
    {
        uint4 z = make_uint4(0, 0, 0, 0);
        for (int i = tid; i < 512; i += THREADS) ((uint4*)hist)[i] = z;
    }
    __syncthreads();
#pragma unroll
    for (int i = 0; i < VEC; ++i) {
        int idx = tid + i * THREADS;
        float4 a = lrow[idx];
        float4 b = nrow[idx];
        atomicAdd(&hist[orderable(a.x + b.x) >> 21], 1u);
        atomicAdd(&hist[orderable(a.y + b.y) >> 21], 1u);
        atomicAdd(&hist[orderable(a.z + b.z) >> 21], 1u);
        atomicAdd(&hist[orderable(a.w + b.w) >> 21], 1u);
    }
    __syncthreads();
    SELECT_BIN(8)
    const unsigned b1 = sel_bin;
    kth = sel_kth;
    __syncthreads();

    // ---- Round 2: bits [20:10] ----
    {
        uint4 z = make_uint4(0, 0, 0, 0);
        for (int i = tid; i < 512; i += THREADS) ((uint4*)hist)[i] = z;
    }
    __syncthreads();
#pragma unroll
    for (int i = 0; i < VEC; ++i) {
        int idx = tid + i * THREADS;
        float4 a = lrow[idx];
        float4 b = nrow[idx];
        unsigned k0 = orderable(a.x + b.x), k1 = orderable(a.y + b.y);
        unsigned k2 = orderable(a.z + b.z), k3 = orderable(a.w + b.w);
        if ((k0 >> 21) == b1) atomicAdd(&hist[(k0 >> 10) & 0x7FFu], 1u);
        if ((k1 >> 21) == b1) atomicAdd(&hist[(k1 >> 10) & 0x7FFu], 1u);
        if ((k2 >> 21) == b1) atomicAdd(&hist[(k2 >> 10) & 0x7FFu], 1u);
        if ((k3 >> 21) == b1) atomicAdd(&hist[(k3 >> 10) & 0x7FFu], 1u);
    }
    __syncthreads();
    SELECT_BIN(8)
    const unsigned b2 = sel_bin;
    kth = sel_kth;
    __syncthreads();

    // ---- Round 3: bits [9:0] ----
    {
        uint4 z = make_uint4(0, 0, 0, 0);
        for (int i = tid; i < 256; i += THREADS) ((uint4*)hist)[i] = z;
    }
    __syncthreads();
    {
        const unsigned pfx = (b1 << 11) | b2;
#pragma unroll
        for (int i = 0; i < VEC; ++i) {
            int idx = tid + i * THREADS;
            float4 a = lrow[idx];
            float4 b = nrow[idx];
            unsigned k0 = orderable(a.x + b.x), k1 = orderable(a.y + b.y);
            unsigned k2 = orderable(a.z + b.z), k3 = orderable(a.w + b.w);
            if ((k0 >> 10) == pfx) atomicAdd(&hist[k0 & 0x3FFu], 1u);
            if ((k1 >> 10) == pfx) atomicAdd(&hist[k1 & 0x3FFu], 1u);
            if ((k2 >> 10) == pfx) atomicAdd(&hist[k2 & 0x3FFu], 1u);
            if ((k3 >> 10) == pfx) atomicAdd(&hist[k3 & 0x3FFu], 1u);
        }
    }
    __syncthreads();
    SELECT_BIN(4)
    const unsigned b3      = sel_bin;
    const unsigned take_eq = sel_kth;
    const unsigned c_eq    = sel_cnt;

    const unsigned T = (b1 << 21) | (b2 << 10) | b3;
    const bool fast = (take_eq == c_eq);

    // ---- Output pass (overwrites row) ----
#pragma unroll
    for (int i = 0; i < VEC; ++i) {
        int idx = tid + i * THREADS;
        float4 a = lrow[idx];
        float4 b = nrow[idx];
        unsigned k0 = orderable(a.x + b.x), k1 = orderable(a.y + b.y);
        unsigned k2 = orderable(a.z + b.z), k3 = orderable(a.w + b.w);
        float4 o;
        o.x = (k0 > T || (fast && k0 == T)) ? 1.0f : 0.0f;
        o.y = (k1 > T || (fast && k1 == T)) ? 1.0f : 0.0f;
        o.z = (k2 > T || (fast && k2 == T)) ? 1.0f : 0.0f;
        o.w = (k3 > T || (fast && k3 == T)) ? 1.0f : 0.0f;
        orow[idx] = o;
    }

    // Boundary-straddling tie: lowest indices win (jax.lax.top_k).
    if (!fast) {
        __syncthreads();
        if (tid == 0) {
            const float* lf = logits + row * (long long)N;
            const float* nf = noise  + row * (long long)N;
            float* of = out + row * (long long)N;
            unsigned c = 0;
            for (int i = 0; i < N; ++i) {
                if (orderable(lf[i] + nf[i]) == T) {
                    of[i] = 1.0f;
                    if (++c == take_eq) break;
                }
            }
        }
    }
#undef SELECT_BIN
}

extern "C" void kernel_launch(void* const* d_in, const int* in_sizes, int n_in,
                              void* d_out, int out_size, void* d_ws, size_t ws_size,
                              hipStream_t stream) {
    const float* logits = (const float*)d_in[0];
    const float* noise  = (const float*)d_in[1];
    float* out = (float*)d_out;
    const int rows = in_sizes[0] / N;   // 2048
    gumbel_topk_onehot<<<rows, THREADS, 0, stream>>>(logits, noise, out);
}